// Round 14
// baseline (81.568 us; speedup 1.0000x reference)
//
#include <hip/hip_runtime.h>
#include <hip/hip_bf16.h>
#include <math.h>

#define NSLICES 1024
#define DIM     768
#define NPTS    256
#define K_REF   17
#define KSPLIT  4
#define KCHUNK  (DIM / KSPLIT)      // 192
#define XSZ     (NSLICES * NPTS)    // 262144 floats per (z, kchunk) partial
#define LPITCH  200                 // LDS row pitch in bf16 (400B: aligned + spread)

// ws float layout — every slot is fully rewritten every call (no zero-init needed)
#define INV_OFF 0                   // 64 partials
#define G_OFF   208                 // 17 scaled reference points
#define SIG_OFF 256                 // 1024 partials
#define XP_OFF  2560                // projection partials

#define EXP2(x) __builtin_amdgcn_exp2f(x)
// y = x * SCALE_A  =>  exp(-0.5(xi-xj)^2) == exp2(-(yi-yj)^2)
#define SCALE_A 0.84932180028801904272f      // sqrt(0.5 * log2(e))
#define INV_N2  1.52587890625e-05f           // 1/256^2
#define T2_SC   4.595588235294118e-4f        // 2/(256*17)

typedef __attribute__((ext_vector_type(8))) short bf16x8_t;   // 8 bf16 = 4 VGPRs
typedef __attribute__((ext_vector_type(4))) float f32x4_t;    // MFMA accumulator

__device__ __forceinline__ float wave_sum(float v) {
#pragma unroll
    for (int o = 32; o; o >>= 1) v += __shfl_xor(v, o, 64);
    return v;
}

__device__ __forceinline__ float block_sum_256(float v, float* wred, int tid) {
    v = wave_sum(v);
    if ((tid & 63) == 0) wred[tid >> 6] = v;
    __syncthreads();
    float r = wred[0] + wred[1] + wred[2] + wred[3];
    __syncthreads();
    return r;
}

__device__ __forceinline__ unsigned pkbf(float lo, float hi) {  // v_cvt_pk_bf16_f32
    union { __hip_bfloat162 h2; unsigned u; } c;
    c.h2 = __float22bfloat162_rn(make_float2(lo, hi));
    return c.u;
}

// ---------------- kernel 1: projection GEMM (bf16 MFMA) + fused inv ---------
// x[m][n] = dot(slices[m], z[n])  (slice normalization dropped: scale-invariant)
// grid: (4 n-tiles, 16 m-tiles, 2*KSPLIT + 1), block 256.
//  z < 2*KSPLIT : proj — 64x64 tile, 4 waves (2x2), KCHUNK=192 staged once as
//                 bf16, 6 MFMA K-steps (m91 gemm_bt fragment recipe).
//  z == 2*KSPLIT: 64 inv blocks (b = mt*4+nt); block 0 also writes scaled g.
__global__ __launch_bounds__(256) void proj_inv_kernel(const float* __restrict__ za,
                                                       const float* __restrict__ zb,
                                                       const float* __restrict__ slices,
                                                       float* __restrict__ w, int npart) {
    const int tid = threadIdx.x;

    if (blockIdx.z == 2 * KSPLIT) {
        // ---- inv path: 64 blocks * 256 threads * 3 float4 = 256*768 ----
        __shared__ float wred[4];
        const int b = blockIdx.y * 4 + blockIdx.x;      // 0..63
        const float4* A = (const float4*)za;
        const float4* B = (const float4*)zb;
        float p = 0.f;
#pragma unroll
        for (int i = 0; i < 3; ++i) {
            int idx = b * 768 + i * 256 + tid;
            float4 a = A[idx], bb = B[idx];
            float dx = a.x - bb.x, dy = a.y - bb.y, dz = a.z - bb.z, dw = a.w - bb.w;
            p += dx * dx + dy * dy + dz * dz + dw * dw;
        }
        float s = block_sum_256(p, wred, tid);
        if (tid == 0) w[INV_OFF + b] = s;
        if (b == 0 && tid < K_REF) {
            float q = 0.01f + 0.06125f * (float)tid;
            w[G_OFF + tid] = erfinvf(2.0f * q - 1.0f) * 1.41421356237309504880f * SCALE_A;
        }
        return;
    }

    // ---- proj path ----
    __shared__ unsigned short lA[64][LPITCH];
    __shared__ unsigned short lB[64][LPITCH];
    const int nt = blockIdx.x;            // 0..3
    const int mt = blockIdx.y;            // 0..15
    const int zi = blockIdx.z >> 2;       // 0..1
    const int kc = blockIdx.z & 3;        // 0..3
    const float* Z = zi ? zb : za;
    const int m0 = mt * 64, n0 = nt * 64;
    const int kbase = kc * KCHUNK;

    // stage: 64 rows x 192 k, f32 -> bf16 (hw v_cvt_pk_bf16_f32 via intrinsic)
    {
        const int r = tid >> 2;           // 0..63
        const int c4 = tid & 3;           // float4 col group
        const float* Ap = slices + (size_t)(m0 + r) * DIM + kbase + c4 * 4;
        const float* Bp = Z + (size_t)(n0 + r) * DIM + kbase + c4 * 4;
        unsigned short* la = &lA[r][c4 * 4];
        unsigned short* lb = &lB[r][c4 * 4];
#pragma unroll
        for (int i = 0; i < 12; ++i) {
            float4 av = *(const float4*)(Ap + i * 16);
            float4 bv = *(const float4*)(Bp + i * 16);
            uint2 ap, bp;
            ap.x = pkbf(av.x, av.y); ap.y = pkbf(av.z, av.w);
            bp.x = pkbf(bv.x, bv.y); bp.y = pkbf(bv.z, bv.w);
            *(uint2*)(la + i * 16) = ap;
            *(uint2*)(lb + i * 16) = bp;
        }
    }
    __syncthreads();

    // compute: 4 waves, each a 32x32 quadrant (2x2 of 16x16 MFMA tiles)
    const int wv = tid >> 6;
    const int wr = wv >> 1, wc = wv & 1;
    const int lane = tid & 63;
    const int fr = lane & 15, fq = lane >> 4;

    f32x4_t acc00 = {0.f, 0.f, 0.f, 0.f}, acc01 = acc00, acc10 = acc00, acc11 = acc00;
    const int ra0 = wr * 32 + fr, ra1 = ra0 + 16;
    const int rb0 = wc * 32 + fr, rb1 = rb0 + 16;
#pragma unroll
    for (int ks = 0; ks < KCHUNK / 32; ++ks) {
        const int k0 = ks * 32 + fq * 8;
        bf16x8_t a0 = *(const bf16x8_t*)&lA[ra0][k0];
        bf16x8_t a1 = *(const bf16x8_t*)&lA[ra1][k0];
        bf16x8_t b0 = *(const bf16x8_t*)&lB[rb0][k0];
        bf16x8_t b1 = *(const bf16x8_t*)&lB[rb1][k0];
        acc00 = __builtin_amdgcn_mfma_f32_16x16x32_bf16(a0, b0, acc00, 0, 0, 0);
        acc01 = __builtin_amdgcn_mfma_f32_16x16x32_bf16(a0, b1, acc01, 0, 0, 0);
        acc10 = __builtin_amdgcn_mfma_f32_16x16x32_bf16(a1, b0, acc10, 0, 0, 0);
        acc11 = __builtin_amdgcn_mfma_f32_16x16x32_bf16(a1, b1, acc11, 0, 0, 0);
    }

    // C-write: row = base_m + fq*4 + j, col = base_n + fr
    const int rowB = m0 + wr * 32 + fq * 4;
    const int colB = n0 + wc * 32 + fr;
    if (npart == KSPLIT) {
        float* X = w + XP_OFF + ((size_t)zi * KSPLIT + kc) * XSZ;
#pragma unroll
        for (int j = 0; j < 4; ++j) {
            X[(size_t)(rowB + j) * NPTS + colB]           = acc00[j];
            X[(size_t)(rowB + j) * NPTS + colB + 16]      = acc01[j];
            X[(size_t)(rowB + 16 + j) * NPTS + colB]      = acc10[j];
            X[(size_t)(rowB + 16 + j) * NPTS + colB + 16] = acc11[j];
        }
    } else {
        float* X = w + XP_OFF + (size_t)zi * XSZ;
#pragma unroll
        for (int j = 0; j < 4; ++j) {
            atomicAdd(X + (size_t)(rowB + j) * NPTS + colB,           acc00[j]);
            atomicAdd(X + (size_t)(rowB + j) * NPTS + colB + 16,      acc01[j]);
            atomicAdd(X + (size_t)(rowB + 16 + j) * NPTS + colB,      acc10[j]);
            atomicAdd(X + (size_t)(rowB + 16 + j) * NPTS + colB + 16, acc11[j]);
        }
    }
}

// ---------------- per-slice sigreg (t1 + t2), both z per block --------------
// One block = one slice m, BOTH z_a and z_b: 8 X-loads in flight, one barrier
// for all 4 reductions, inner loop runs 8 independent exp chains (4 A + 4 B).
// Factored exp: exp2(-(yv-yj)^2) = exp2(-yv^2)*exp2(fma(2yv,yj,-yj^2)).
// t1 off-diag via circular offsets o=1..128: total = 2*sum - S_128 (+ diag N).
// grid: NSLICES blocks of 256.
template <int NPART>
__global__ __launch_bounds__(256) void sigreg_kernel(float* __restrict__ w) {
    __shared__ float2 ysA[2 * NPTS];   // duplicated (y, -y^2): base + imm offset reads
    __shared__ float2 ysB[2 * NPTS];
    __shared__ float2 gsh2[K_REF];
    __shared__ float wred[4][4];       // [quantity][wave]
    const int m = blockIdx.x;
    const int tid = threadIdx.x;

    const float* XbA = w + XP_OFF + (size_t)m * NPTS + tid;
    const float* XbB = XbA + (size_t)NPART * XSZ;
    float xpA[NPART], xpB[NPART];
#pragma unroll
    for (int p = 0; p < NPART; ++p) {                    // 8 loads in flight
        xpA[p] = XbA[(size_t)p * XSZ];
        xpB[p] = XbB[(size_t)p * XSZ];
    }
    if (tid < K_REF) {
        float gv = w[G_OFF + tid];
        gsh2[tid] = make_float2(gv, -gv * gv);
    }
    float xa = 0.f, xb = 0.f;
#pragma unroll
    for (int p = 0; p < NPART; ++p) { xa += xpA[p]; xb += xpB[p]; }

    // 4 interleaved wave reductions, one barrier
    float sA = xa, sA2 = xa * xa, sB = xb, sB2 = xb * xb;
#pragma unroll
    for (int o = 32; o; o >>= 1) {
        sA  += __shfl_xor(sA,  o, 64);
        sA2 += __shfl_xor(sA2, o, 64);
        sB  += __shfl_xor(sB,  o, 64);
        sB2 += __shfl_xor(sB2, o, 64);
    }
    if ((tid & 63) == 0) {
        int wv = tid >> 6;
        wred[0][wv] = sA; wred[1][wv] = sA2; wred[2][wv] = sB; wred[3][wv] = sB2;
    }
    __syncthreads();
    float sumA  = (wred[0][0] + wred[0][1]) + (wred[0][2] + wred[0][3]);
    float sumA2 = (wred[1][0] + wred[1][1]) + (wred[1][2] + wred[1][3]);
    float sumB  = (wred[2][0] + wred[2][1]) + (wred[2][2] + wred[2][3]);
    float sumB2 = (wred[3][0] + wred[3][1]) + (wred[3][2] + wred[3][3]);
    float muA = sumA * (1.0f / NPTS), muB = sumB * (1.0f / NPTS);
    float ssA = sumA2 - muA * sumA,   ssB = sumB2 - muB * sumB;
    float sdA = sqrtf(ssA * (1.0f / (NPTS - 1))) + 1e-6f;
    float sdB = sqrtf(ssB * (1.0f / (NPTS - 1))) + 1e-6f;
    float yA = (xa - muA) / sdA * SCALE_A;
    float yB = (xb - muB) / sdB * SCALE_A;
    float2 prA = make_float2(yA, -yA * yA);
    float2 prB = make_float2(yB, -yB * yB);
    ysA[tid] = prA; ysA[tid + NPTS] = prA;
    ysB[tid] = prB; ysB[tid + NPTS] = prB;
    __syncthreads();

    const float avA = 2.0f * yA, avB = 2.0f * yB;
    const float facA = EXP2(-yA * yA), facB = EXP2(-yB * yB);
    float a0 = 0.f, a1 = 0.f, a2 = 0.f, a3 = 0.f;
    float b0 = 0.f, b1 = 0.f, b2 = 0.f, b3 = 0.f;
#pragma unroll
    for (int t = 0; t < 32; ++t) {                 // o = 4t+1 .. 4t+4 (covers 1..128)
        float2 kA1 = ysA[tid + 4 * t + 1];
        float2 kA2 = ysA[tid + 4 * t + 2];
        float2 kA3 = ysA[tid + 4 * t + 3];
        float2 kA4 = ysA[tid + 4 * t + 4];
        float2 kB1 = ysB[tid + 4 * t + 1];
        float2 kB2 = ysB[tid + 4 * t + 2];
        float2 kB3 = ysB[tid + 4 * t + 3];
        float2 kB4 = ysB[tid + 4 * t + 4];
        a0 += EXP2(fmaf(avA, kA1.x, kA1.y));
        a1 += EXP2(fmaf(avA, kA2.x, kA2.y));
        a2 += EXP2(fmaf(avA, kA3.x, kA3.y));
        a3 += EXP2(fmaf(avA, kA4.x, kA4.y));
        b0 += EXP2(fmaf(avB, kB1.x, kB1.y));
        b1 += EXP2(fmaf(avB, kB2.x, kB2.y));
        b2 += EXP2(fmaf(avB, kB3.x, kB3.y));
        b3 += EXP2(fmaf(avB, kB4.x, kB4.y));
    }
    float2 klA = ysA[tid + 128];
    float2 klB = ysB[tid + 128];
    float s128A = facA * EXP2(fmaf(avA, klA.x, klA.y));
    float s128B = facB * EXP2(fmaf(avB, klB.x, klB.y));
    float s1A = ((a0 + a1) + (a2 + a3)) * facA;    // sum over o=1..128
    float s1B = ((b0 + b1) + (b2 + b3)) * facB;
    float sgA = 0.f, sgB = 0.f;
#pragma unroll
    for (int k = 0; k < K_REF; ++k) {
        float2 g = gsh2[k];
        sgA += EXP2(fmaf(avA, g.x, g.y));
        sgB += EXP2(fmaf(avB, g.x, g.y));
    }
    sgA *= facA; sgB *= facB;
    // off-diag = 2*sum(o=1..128) - S_128 ; diagonal N added at tid 0 (both z)
    float c = (2.0f * (s1A + s1B) - s128A - s128B) * INV_N2 - (sgA + sgB) * T2_SC;
    if (tid == 0) c += 2.0f * (float)NPTS * INV_N2;
    float v = wave_sum(c);
    if ((tid & 63) == 0) wred[0][tid >> 6] = v;    // safe: all reads were pre-barrier
    __syncthreads();
    if (tid == 0) {
        float tot = (wred[0][0] + wred[0][1]) + (wred[0][2] + wred[0][3]);
        w[SIG_OFF + m] = tot * (0.5f / (float)NSLICES);
    }
}

// ---------------- final: reduce slots + t3 + combine ------------------------
__global__ __launch_bounds__(256) void final_kernel(const float* __restrict__ w,
                                                    float* __restrict__ out) {
    __shared__ float wred[4];
    __shared__ float gsh[K_REF];
    const int tid = threadIdx.x;
    if (tid < K_REF) gsh[tid] = w[G_OFF + tid];
    float sv = 0.f;
#pragma unroll
    for (int i = 0; i < 4; ++i) sv += w[SIG_OFF + i * 256 + tid];
    float iv = (tid < 64) ? w[INV_OFF + tid] : 0.f;
    float sig = block_sum_256(sv, wred, tid);
    float inv = block_sum_256(iv, wred, tid);
    // t3 over 289 pairs, parallel (gsh already scaled by SCALE_A)
    float t3p = 0.f;
    for (int idx = tid; idx < K_REF * K_REF; idx += 256) {
        int k = idx / K_REF, l = idx - k * K_REF;
        float d = gsh[k] - gsh[l];
        t3p += EXP2(-(d * d));
    }
    float t3 = block_sum_256(t3p, wred, tid) * (1.0f / ((float)K_REF * (float)K_REF));
    if (tid == 0) {
        out[0] = 25.0f * inv * (1.0f / ((float)NPTS * (float)DIM))
               + 25.0f * (sig + t3);
    }
}

extern "C" void kernel_launch(void* const* d_in, const int* in_sizes, int n_in,
                              void* d_out, int out_size, void* d_ws, size_t ws_size,
                              hipStream_t stream) {
    const float* za = (const float*)d_in[0];
    const float* zb = (const float*)d_in[1];
    const float* slices = (const float*)d_in[2];
    float* out = (float*)d_out;
    float* w = (float*)d_ws;

    const size_t need_full = (size_t)(XP_OFF + 2 * KSPLIT * XSZ) * sizeof(float); // ~8.4 MB
    const int npart = (ws_size >= need_full) ? KSPLIT : 1;

    if (npart == 1)   // fallback only (harness ws is plenty; never taken)
        hipMemsetAsync(w + XP_OFF, 0, (size_t)2 * XSZ * sizeof(float), stream);

    dim3 pg(4, 16, 2 * KSPLIT + 1);
    proj_inv_kernel<<<pg, 256, 0, stream>>>(za, zb, slices, w, npart);
    if (npart == KSPLIT)
        sigreg_kernel<KSPLIT><<<NSLICES, 256, 0, stream>>>(w);
    else
        sigreg_kernel<1><<<NSLICES, 256, 0, stream>>>(w);
    final_kernel<<<1, 256, 0, stream>>>(w, out);
}